// Round 1
// baseline (155.608 us; speedup 1.0000x reference)
//
#include <hip/hip_runtime.h>

typedef short short8 __attribute__((ext_vector_type(8)));
typedef float f32x4 __attribute__((ext_vector_type(4)));

#define NTOK (8 * 16 * 32 * 32)  // 131072 tokens
#define NE 1024
#define ED 64
#define TPB 256
#define MBLK 128                 // tokens per block = 4 waves x 32
#define NMF 2                    // m-frags per wave (32 tokens)
#define WKEY (1 << 18)           // candidate window in key units (~3.9e-3 in dist)
#define SCALE (-131072.0f)       // -2^17: exact po2 scale — applied to B ONLY

__device__ __forceinline__ unsigned short bf16_rtne(float f) {
    unsigned u = __float_as_uint(f);
    return (unsigned short)((u + 0x7FFFu + ((u >> 16) & 1u)) >> 16);
}
__device__ __forceinline__ float bf16_to_f32(unsigned short h) {
    return __uint_as_float(((unsigned)h) << 16);
}

// EXACT distance — identical structure/order to the R1 kernel (absmax 0 vs numpy).
__device__ float exact_dist(const float* __restrict__ z, const float* __restrict__ emb,
                            int t, int e) {
    const float* zt = z + (size_t)t * ED;
    const float* ep = emb + (size_t)e * ED;
    float r0 = 0.f, r1 = 0.f, r2 = 0.f, r3 = 0.f;
    float r4 = 0.f, r5 = 0.f, r6 = 0.f, r7 = 0.f;
    for (int d = 0; d < ED; d += 8) {
        r0 += zt[d + 0] * zt[d + 0];
        r1 += zt[d + 1] * zt[d + 1];
        r2 += zt[d + 2] * zt[d + 2];
        r3 += zt[d + 3] * zt[d + 3];
        r4 += zt[d + 4] * zt[d + 4];
        r5 += zt[d + 5] * zt[d + 5];
        r6 += zt[d + 6] * zt[d + 6];
        r7 += zt[d + 7] * zt[d + 7];
    }
    float s1 = ((r0 + r1) + (r2 + r3)) + ((r4 + r5) + (r6 + r7));
    float q0 = 0.f, q1 = 0.f, q2 = 0.f, q3 = 0.f;
    float q4 = 0.f, q5 = 0.f, q6 = 0.f, q7 = 0.f;
    for (int d = 0; d < ED; d += 8) {
        float v0 = ep[d + 0], v1 = ep[d + 1], v2 = ep[d + 2], v3 = ep[d + 3];
        float v4 = ep[d + 4], v5 = ep[d + 5], v6 = ep[d + 6], v7 = ep[d + 7];
        q0 += v0 * v0; q1 += v1 * v1; q2 += v2 * v2; q3 += v3 * v3;
        q4 += v4 * v4; q5 += v5 * v5; q6 += v6 * v6; q7 += v7 * v7;
    }
    float s2 = ((q0 + q1) + (q2 + q3)) + ((q4 + q5) + (q6 + q7));
    float a0 = 0.f, a1 = 0.f, a2 = 0.f, a3 = 0.f;
    for (int d = 0; d < ED; d += 4) {
        a0 = fmaf(zt[d + 0], ep[d + 0], a0);
        a1 = fmaf(zt[d + 1], ep[d + 1], a1);
        a2 = fmaf(zt[d + 2], ep[d + 2], a2);
        a3 = fmaf(zt[d + 3], ep[d + 3], a3);
    }
    float g = (a0 + a1) + (a2 + a3);
    return (s1 + s2) - 2.0f * g;
}

// ---- prep: unchanged (B-fragments hi/lo bf16, -2^17-scaled, MFMA order; s2) ----
__global__ __launch_bounds__(128) void vq_prep(
    const float* __restrict__ emb,
    unsigned short* __restrict__ bfH,
    unsigned short* __restrict__ bfL,
    float* __restrict__ s2s)
{
    const int f = blockIdx.x * 128 + threadIdx.x;  // 0..8191 fragment id
    const int col = f & 15;
    const int quad = (f >> 4) & 3;
    const int kb = (f >> 6) & 1;
    const int nt = f >> 7;
    const int e = nt * 16 + col;
    const int k0 = kb * 32 + quad * 8;

    const float* p = emb + (size_t)e * ED + k0;
    float4 v0 = *(const float4*)p;
    float4 v1 = *(const float4*)(p + 4);
    float vs[8] = {v0.x, v0.y, v0.z, v0.w, v1.x, v1.y, v1.z, v1.w};
    short8 h, l;
#pragma unroll
    for (int j = 0; j < 8; ++j) {
        float x = vs[j] * SCALE;              // exact po2 scaling (B side only!)
        unsigned short hb = bf16_rtne(x);
        float hf = bf16_to_f32(hb);
        unsigned short lb = bf16_rtne(x - hf);
        h[j] = (short)hb;
        l[j] = (short)lb;
    }
    *(short8*)&bfH[(size_t)f * 8] = h;
    *(short8*)&bfL[(size_t)f * 8] = l;

    if (f < 4096) {
        const int row = f >> 2;
        const float4* rp = (const float4*)(emb + (size_t)row * ED + (f & 3) * 16);
        float4 a = rp[0], b = rp[1], c = rp[2], d = rp[3];
        float s = a.x * a.x + a.y * a.y + a.z * a.z + a.w * a.w
                + b.x * b.x + b.y * b.y + b.z * b.z + b.w * b.w
                + c.x * c.x + c.y * c.y + c.z * c.z + c.w * c.w
                + d.x * d.x + d.y * d.y + d.z * d.z + d.w * d.w;
        s += __shfl_xor(s, 1);
        s += __shfl_xor(s, 2);
        if ((f & 3) == 0) s2s[row] = s * 65536.0f;
    }
}

// ---- main: NO per-iteration barriers. Each wave loads its 4 B-fragments
//      (lane-contiguous 16B each) directly from global (L1/L2-resident, B is
//      only 256 KB total) into registers, 1-deep prefetched. This removes the
//      64x { vmcnt(0) drain + s_barrier } critical path of the LDS-staged
//      version; waves pipeline independently. ----
__global__ void __launch_bounds__(TPB)
__attribute__((amdgpu_waves_per_eu(4))) vq_main(
    const float* __restrict__ z,
    const float* __restrict__ emb,
    const unsigned short* __restrict__ bfH,
    const unsigned short* __restrict__ bfL,
    const float* __restrict__ s2s_g,
    float* __restrict__ zq_out,
    float* __restrict__ idx_out)
{
    __shared__ float s2L[NE];
    __shared__ int idx_lds[MBLK];

    const int tid = threadIdx.x;
    const int lane = tid & 63;
    const int wv = __builtin_amdgcn_readfirstlane(tid >> 6);
    const int col = lane & 15;
    const int quad = lane >> 4;
    const int blockTok = blockIdx.x * MBLK;

    for (int i = tid; i < NE; i += TPB) s2L[i] = s2s_g[i];

    // ---- A-fragments: 32 tokens per wave (2 m-frags), hi/lo bf16, UNSCALED ----
    short8 Ah[NMF][2], Al[NMF][2];
#pragma unroll
    for (int mf = 0; mf < NMF; ++mf) {
#pragma unroll
        for (int kf = 0; kf < 2; ++kf) {
            const float* zp = z + (size_t)(blockTok + wv * 32 + mf * 16 + col) * ED
                              + kf * 32 + quad * 8;
            float4 v0 = *(const float4*)zp;
            float4 v1 = *(const float4*)(zp + 4);
            float vs[8] = {v0.x, v0.y, v0.z, v0.w, v1.x, v1.y, v1.z, v1.w};
            short8 h, l;
#pragma unroll
            for (int j = 0; j < 8; ++j) {
                float x = vs[j];              // NO scale on A
                unsigned short hb = bf16_rtne(x);
                float hf = bf16_to_f32(hb);
                unsigned short lb = bf16_rtne(x - hf);
                h[j] = (short)hb;
                l[j] = (short)lb;
            }
            Ah[mf][kf] = h;
            Al[mf][kf] = l;
        }
    }

    int aK[NMF][4], bK[NMF][4];
#pragma unroll
    for (int mf = 0; mf < NMF; ++mf)
#pragma unroll
        for (int r = 0; r < 4; ++r) { aK[mf][r] = 0x7FFFFFFF; bK[mf][r] = 0x7FFFFFFF; }

    // B-fragment streams: per nt-slice, 128 fragments of 16B; lane's frags are
    // u4[nt*128 + lane] (k-frag 0) and u4[nt*128 + 64 + lane] (k-frag 1).
    const uint4* u4H = (const uint4*)bfH;
    const uint4* u4L = (const uint4*)bfL;

    // prologue: load slice 0
    uint4 cB0 = u4H[lane];
    uint4 cB1 = u4H[64 + lane];
    uint4 cB2 = u4L[lane];
    uint4 cB3 = u4L[64 + lane];

    __syncthreads();  // s2L ready (only barrier before the epilogue)

    for (int nt = 0; nt < 64; ++nt) {
        // issue next slice's loads (wrap at the end: redundant re-load of slice
        // 0, never consumed — keeps the loop branch-free for pipelining)
        const int nb = (((nt + 1) & 63) << 7) + lane;
        uint4 nB0 = u4H[nb];
        uint4 nB1 = u4H[nb + 64];
        uint4 nB2 = u4L[nb];
        uint4 nB3 = u4L[nb + 64];

        short8 Bh0 = __builtin_bit_cast(short8, cB0);
        short8 Bh1 = __builtin_bit_cast(short8, cB1);
        short8 Bl0 = __builtin_bit_cast(short8, cB2);
        short8 Bl1 = __builtin_bit_cast(short8, cB3);

        const float s2v = s2L[nt * 16 + col];
        const int e = nt * 16 + col;
#pragma unroll
        for (int mf = 0; mf < NMF; ++mf) {
            f32x4 cc = {s2v, s2v, s2v, s2v};  // acc = s2*2^16 + A·(-2^17 e) = 2^16(s2-2g)
            cc = __builtin_amdgcn_mfma_f32_16x16x32_bf16(Ah[mf][0], Bh0, cc, 0, 0, 0);
            cc = __builtin_amdgcn_mfma_f32_16x16x32_bf16(Ah[mf][1], Bh1, cc, 0, 0, 0);
            cc = __builtin_amdgcn_mfma_f32_16x16x32_bf16(Al[mf][0], Bh0, cc, 0, 0, 0);
            cc = __builtin_amdgcn_mfma_f32_16x16x32_bf16(Al[mf][1], Bh1, cc, 0, 0, 0);
            cc = __builtin_amdgcn_mfma_f32_16x16x32_bf16(Ah[mf][0], Bl0, cc, 0, 0, 0);
            cc = __builtin_amdgcn_mfma_f32_16x16x32_bf16(Ah[mf][1], Bl1, cc, 0, 0, 0);
#pragma unroll
            for (int r = 0; r < 4; ++r) {
                int key = ((int)cc[r]) * 1024 + e;  // unique, monotone, tie->low e
                const int a0 = aK[mf][r];
                int t1 = min(a0, key);
                // bK' = min(bK, max(a0, key)) == med3(a0, bK, key) since a0<=bK
                int med;
                asm("v_med3_i32 %0, %1, %2, %3"
                    : "=v"(med) : "v"(a0), "v"(bK[mf][r]), "v"(key));
                bK[mf][r] = med;
                aK[mf][r] = t1;
            }
        }

        cB0 = nB0; cB1 = nB1; cB2 = nB2; cB3 = nB3;
    }

    // ---- phase B: resolve argmin per token (16-lane groups) ----
#pragma unroll
    for (int mf = 0; mf < NMF; ++mf) {
#pragma unroll
        for (int r = 0; r < 4; ++r) {
            const int a0 = aK[mf][r], b0 = bK[mf][r];
            int A = a0, B = b0;
#pragma unroll
            for (int off = 1; off < 16; off <<= 1) {
                int A2 = __shfl_xor(A, off);
                int B2 = __shfl_xor(B, off);
                int lo = min(A, A2), hi = max(A, A2);
                B = min(min(B, B2), hi);
                A = lo;
            }
            int winner = A & 1023;
            if (B - A <= WKEY) {  // contested: exact fp32 re-check of candidates
                const int t = blockTok + wv * 32 + mf * 16 + quad * 4 + r;
                float dbest = 3.4e38f;
                int ibest = 1 << 30;
                if (a0 <= A + WKEY) {
                    int e = a0 & 1023;
                    float d = exact_dist(z, emb, t, e);
                    if (d < dbest || (d == dbest && e < ibest)) { dbest = d; ibest = e; }
                }
                if (b0 <= A + WKEY) {
                    int e = b0 & 1023;
                    float d = exact_dist(z, emb, t, e);
                    if (d < dbest || (d == dbest && e < ibest)) { dbest = d; ibest = e; }
                }
#pragma unroll
                for (int off = 1; off < 16; off <<= 1) {
                    float d2 = __shfl_xor(dbest, off);
                    int i2 = __shfl_xor(ibest, off);
                    if (d2 < dbest || (d2 == dbest && i2 < ibest)) { dbest = d2; ibest = i2; }
                }
                winner = ibest;
            }
            if (col == 0) idx_lds[wv * 32 + mf * 16 + quad * 4 + r] = winner;
        }
    }

    __syncthreads();

    // ---- outputs ----
    if (tid < MBLK) idx_out[blockTok + tid] = (float)idx_lds[tid];
    const float4* emb_f4 = (const float4*)emb;
    float4* zq_f4 = (float4*)zq_out;
#pragma unroll
    for (int i = 0; i < MBLK * 16 / TPB; ++i) {  // 8 iters
        int item = tid + i * TPB;
        int tl = item >> 4, f4 = item & 15;
        int wi = idx_lds[tl];
        zq_f4[(size_t)(blockTok + tl) * 16 + f4] = emb_f4[(size_t)wi * 16 + f4];
    }
}

extern "C" void kernel_launch(void* const* d_in, const int* in_sizes, int n_in,
                              void* d_out, int out_size, void* d_ws, size_t ws_size,
                              hipStream_t stream) {
    const float* z = (const float*)d_in[0];
    const float* emb = (const float*)d_in[1];
    float* out = (float*)d_out;
    float* zq = out;                       // 131072*64 floats
    float* idx = out + (size_t)NTOK * ED;  // 131072 floats

    // ws layout: s2s (4KB) | bfH (128KB) | bfL (128KB)
    char* ws = (char*)d_ws;
    float* s2s = (float*)ws;
    unsigned short* bfH = (unsigned short*)(ws + 4096);
    unsigned short* bfL = (unsigned short*)(ws + 4096 + 131072);

    vq_prep<<<64, 128, 0, stream>>>(emb, bfH, bfL, s2s);
    vq_main<<<NTOK / MBLK, TPB, 0, stream>>>(z, emb, bfH, bfL, s2s, zq, idx);
}

// Round 2
// 140.091 us; speedup vs baseline: 1.1108x; 1.1108x over previous
//
#include <hip/hip_runtime.h>

typedef short short8 __attribute__((ext_vector_type(8)));
typedef float f32x4 __attribute__((ext_vector_type(4)));

#define NTOK (8 * 16 * 32 * 32)  // 131072 tokens
#define NE 1024
#define ED 64
#define TPB 256
#define MBLK 256                 // tokens per block = 4 waves x 64
#define NMF 4                    // m-frags per wave (64 tokens) — halves B traffic/pair
#define WKEY (1 << 18)           // candidate window in key units (~3.9e-3 in dist)
#define SCALE (-131072.0f)       // -2^17: exact po2 scale — applied to B ONLY

__device__ __forceinline__ unsigned short bf16_rtne(float f) {
    unsigned u = __float_as_uint(f);
    return (unsigned short)((u + 0x7FFFu + ((u >> 16) & 1u)) >> 16);
}
__device__ __forceinline__ float bf16_to_f32(unsigned short h) {
    return __uint_as_float(((unsigned)h) << 16);
}

// EXACT distance — identical structure/order to the R1 kernel (absmax 0 vs numpy).
__device__ float exact_dist(const float* __restrict__ z, const float* __restrict__ emb,
                            int t, int e) {
    const float* zt = z + (size_t)t * ED;
    const float* ep = emb + (size_t)e * ED;
    float r0 = 0.f, r1 = 0.f, r2 = 0.f, r3 = 0.f;
    float r4 = 0.f, r5 = 0.f, r6 = 0.f, r7 = 0.f;
    for (int d = 0; d < ED; d += 8) {
        r0 += zt[d + 0] * zt[d + 0];
        r1 += zt[d + 1] * zt[d + 1];
        r2 += zt[d + 2] * zt[d + 2];
        r3 += zt[d + 3] * zt[d + 3];
        r4 += zt[d + 4] * zt[d + 4];
        r5 += zt[d + 5] * zt[d + 5];
        r6 += zt[d + 6] * zt[d + 6];
        r7 += zt[d + 7] * zt[d + 7];
    }
    float s1 = ((r0 + r1) + (r2 + r3)) + ((r4 + r5) + (r6 + r7));
    float q0 = 0.f, q1 = 0.f, q2 = 0.f, q3 = 0.f;
    float q4 = 0.f, q5 = 0.f, q6 = 0.f, q7 = 0.f;
    for (int d = 0; d < ED; d += 8) {
        float v0 = ep[d + 0], v1 = ep[d + 1], v2 = ep[d + 2], v3 = ep[d + 3];
        float v4 = ep[d + 4], v5 = ep[d + 5], v6 = ep[d + 6], v7 = ep[d + 7];
        q0 += v0 * v0; q1 += v1 * v1; q2 += v2 * v2; q3 += v3 * v3;
        q4 += v4 * v4; q5 += v5 * v5; q6 += v6 * v6; q7 += v7 * v7;
    }
    float s2 = ((q0 + q1) + (q2 + q3)) + ((q4 + q5) + (q6 + q7));
    float a0 = 0.f, a1 = 0.f, a2 = 0.f, a3 = 0.f;
    for (int d = 0; d < ED; d += 4) {
        a0 = fmaf(zt[d + 0], ep[d + 0], a0);
        a1 = fmaf(zt[d + 1], ep[d + 1], a1);
        a2 = fmaf(zt[d + 2], ep[d + 2], a2);
        a3 = fmaf(zt[d + 3], ep[d + 3], a3);
    }
    float g = (a0 + a1) + (a2 + a3);
    return (s1 + s2) - 2.0f * g;
}

// ---- prep: unchanged (B-fragments hi/lo bf16, -2^17-scaled, MFMA order; s2) ----
__global__ __launch_bounds__(128) void vq_prep(
    const float* __restrict__ emb,
    unsigned short* __restrict__ bfH,
    unsigned short* __restrict__ bfL,
    float* __restrict__ s2s)
{
    const int f = blockIdx.x * 128 + threadIdx.x;  // 0..8191 fragment id
    const int col = f & 15;
    const int quad = (f >> 4) & 3;
    const int kb = (f >> 6) & 1;
    const int nt = f >> 7;
    const int e = nt * 16 + col;
    const int k0 = kb * 32 + quad * 8;

    const float* p = emb + (size_t)e * ED + k0;
    float4 v0 = *(const float4*)p;
    float4 v1 = *(const float4*)(p + 4);
    float vs[8] = {v0.x, v0.y, v0.z, v0.w, v1.x, v1.y, v1.z, v1.w};
    short8 h, l;
#pragma unroll
    for (int j = 0; j < 8; ++j) {
        float x = vs[j] * SCALE;              // exact po2 scaling (B side only!)
        unsigned short hb = bf16_rtne(x);
        float hf = bf16_to_f32(hb);
        unsigned short lb = bf16_rtne(x - hf);
        h[j] = (short)hb;
        l[j] = (short)lb;
    }
    *(short8*)&bfH[(size_t)f * 8] = h;
    *(short8*)&bfL[(size_t)f * 8] = l;

    if (f < 4096) {
        const int row = f >> 2;
        const float4* rp = (const float4*)(emb + (size_t)row * ED + (f & 3) * 16);
        float4 a = rp[0], b = rp[1], c = rp[2], d = rp[3];
        float s = a.x * a.x + a.y * a.y + a.z * a.z + a.w * a.w
                + b.x * b.x + b.y * b.y + b.z * b.z + b.w * b.w
                + c.x * c.x + c.y * c.y + c.z * c.z + c.w * c.w
                + d.x * d.x + d.y * d.y + d.z * d.z + d.w * d.w;
        s += __shfl_xor(s, 1);
        s += __shfl_xor(s, 2);
        if ((f & 3) == 0) s2s[row] = s * 65536.0f;
    }
}

// ---- main: 64 tokens/wave (NMF=4). Each 4KB B-slice fetched per wave now
//      feeds 24 MFMAs (1024 distance pairs) instead of 12/512 — B operand
//      delivery drops from ~8 B/pair to 4 B/pair (1 GB -> 0.5 GB chip-wide),
//      putting it below the 20.5 us MFMA-pipe floor. 4 independent MFMA
//      chains per wave supply the ILP that occupancy (2 waves/SIMD) no
//      longer needs to. ----
__global__ void __launch_bounds__(TPB) vq_main(
    const float* __restrict__ z,
    const float* __restrict__ emb,
    const unsigned short* __restrict__ bfH,
    const unsigned short* __restrict__ bfL,
    const float* __restrict__ s2s_g,
    float* __restrict__ zq_out,
    float* __restrict__ idx_out)
{
    __shared__ float s2L[NE];
    __shared__ int idx_lds[MBLK];

    const int tid = threadIdx.x;
    const int lane = tid & 63;
    const int wv = __builtin_amdgcn_readfirstlane(tid >> 6);
    const int col = lane & 15;
    const int quad = lane >> 4;
    const int blockTok = blockIdx.x * MBLK;

    for (int i = tid; i < NE; i += TPB) s2L[i] = s2s_g[i];

    // ---- A-fragments: 64 tokens per wave (4 m-frags), hi/lo bf16, UNSCALED ----
    short8 Ah[NMF][2], Al[NMF][2];
#pragma unroll
    for (int mf = 0; mf < NMF; ++mf) {
#pragma unroll
        for (int kf = 0; kf < 2; ++kf) {
            const float* zp = z + (size_t)(blockTok + wv * 64 + mf * 16 + col) * ED
                              + kf * 32 + quad * 8;
            float4 v0 = *(const float4*)zp;
            float4 v1 = *(const float4*)(zp + 4);
            float vs[8] = {v0.x, v0.y, v0.z, v0.w, v1.x, v1.y, v1.z, v1.w};
            short8 h, l;
#pragma unroll
            for (int j = 0; j < 8; ++j) {
                float x = vs[j];              // NO scale on A
                unsigned short hb = bf16_rtne(x);
                float hf = bf16_to_f32(hb);
                unsigned short lb = bf16_rtne(x - hf);
                h[j] = (short)hb;
                l[j] = (short)lb;
            }
            Ah[mf][kf] = h;
            Al[mf][kf] = l;
        }
    }

    int aK[NMF][4], bK[NMF][4];
#pragma unroll
    for (int mf = 0; mf < NMF; ++mf)
#pragma unroll
        for (int r = 0; r < 4; ++r) { aK[mf][r] = 0x7FFFFFFF; bK[mf][r] = 0x7FFFFFFF; }

    // B-fragment streams: per nt-slice, 128 fragments of 16B; lane's frags are
    // u4[nt*128 + lane] (k-frag 0) and u4[nt*128 + 64 + lane] (k-frag 1).
    const uint4* u4H = (const uint4*)bfH;
    const uint4* u4L = (const uint4*)bfL;

    // prologue: load slice 0
    uint4 cB0 = u4H[lane];
    uint4 cB1 = u4H[64 + lane];
    uint4 cB2 = u4L[lane];
    uint4 cB3 = u4L[64 + lane];

    __syncthreads();  // s2L ready (only barrier before the epilogue)

    for (int nt = 0; nt < 64; ++nt) {
        // issue next slice's loads (wrap at the end: redundant re-load of slice
        // 0, never consumed — keeps the loop branch-free for pipelining)
        const int nb = (((nt + 1) & 63) << 7) + lane;
        uint4 nB0 = u4H[nb];
        uint4 nB1 = u4H[nb + 64];
        uint4 nB2 = u4L[nb];
        uint4 nB3 = u4L[nb + 64];

        short8 Bh0 = __builtin_bit_cast(short8, cB0);
        short8 Bh1 = __builtin_bit_cast(short8, cB1);
        short8 Bl0 = __builtin_bit_cast(short8, cB2);
        short8 Bl1 = __builtin_bit_cast(short8, cB3);

        const float s2v = s2L[nt * 16 + col];
        const int e = nt * 16 + col;
#pragma unroll
        for (int mf = 0; mf < NMF; ++mf) {
            f32x4 cc = {s2v, s2v, s2v, s2v};  // acc = s2*2^16 + A·(-2^17 e) = 2^16(s2-2g)
            cc = __builtin_amdgcn_mfma_f32_16x16x32_bf16(Ah[mf][0], Bh0, cc, 0, 0, 0);
            cc = __builtin_amdgcn_mfma_f32_16x16x32_bf16(Ah[mf][1], Bh1, cc, 0, 0, 0);
            cc = __builtin_amdgcn_mfma_f32_16x16x32_bf16(Al[mf][0], Bh0, cc, 0, 0, 0);
            cc = __builtin_amdgcn_mfma_f32_16x16x32_bf16(Al[mf][1], Bh1, cc, 0, 0, 0);
            cc = __builtin_amdgcn_mfma_f32_16x16x32_bf16(Ah[mf][0], Bl0, cc, 0, 0, 0);
            cc = __builtin_amdgcn_mfma_f32_16x16x32_bf16(Ah[mf][1], Bl1, cc, 0, 0, 0);
#pragma unroll
            for (int r = 0; r < 4; ++r) {
                int key = ((int)cc[r]) * 1024 + e;  // unique, monotone, tie->low e
                const int a0 = aK[mf][r];
                int t1 = min(a0, key);
                // bK' = min(bK, max(a0, key)) == med3(a0, bK, key) since a0<=bK
                int med;
                asm("v_med3_i32 %0, %1, %2, %3"
                    : "=v"(med) : "v"(a0), "v"(bK[mf][r]), "v"(key));
                bK[mf][r] = med;
                aK[mf][r] = t1;
            }
        }

        cB0 = nB0; cB1 = nB1; cB2 = nB2; cB3 = nB3;
    }

    // ---- phase B: resolve argmin per token (16-lane groups) ----
#pragma unroll
    for (int mf = 0; mf < NMF; ++mf) {
#pragma unroll
        for (int r = 0; r < 4; ++r) {
            const int a0 = aK[mf][r], b0 = bK[mf][r];
            int A = a0, B = b0;
#pragma unroll
            for (int off = 1; off < 16; off <<= 1) {
                int A2 = __shfl_xor(A, off);
                int B2 = __shfl_xor(B, off);
                int lo = min(A, A2), hi = max(A, A2);
                B = min(min(B, B2), hi);
                A = lo;
            }
            int winner = A & 1023;
            if (B - A <= WKEY) {  // contested: exact fp32 re-check of candidates
                const int t = blockTok + wv * 64 + mf * 16 + quad * 4 + r;
                float dbest = 3.4e38f;
                int ibest = 1 << 30;
                if (a0 <= A + WKEY) {
                    int e = a0 & 1023;
                    float d = exact_dist(z, emb, t, e);
                    if (d < dbest || (d == dbest && e < ibest)) { dbest = d; ibest = e; }
                }
                if (b0 <= A + WKEY) {
                    int e = b0 & 1023;
                    float d = exact_dist(z, emb, t, e);
                    if (d < dbest || (d == dbest && e < ibest)) { dbest = d; ibest = e; }
                }
#pragma unroll
                for (int off = 1; off < 16; off <<= 1) {
                    float d2 = __shfl_xor(dbest, off);
                    int i2 = __shfl_xor(ibest, off);
                    if (d2 < dbest || (d2 == dbest && i2 < ibest)) { dbest = d2; ibest = i2; }
                }
                winner = ibest;
            }
            if (col == 0) idx_lds[wv * 64 + mf * 16 + quad * 4 + r] = winner;
        }
    }

    __syncthreads();

    // ---- outputs ----
    idx_out[blockTok + tid] = (float)idx_lds[tid];
    const float4* emb_f4 = (const float4*)emb;
    float4* zq_f4 = (float4*)zq_out;
#pragma unroll
    for (int i = 0; i < MBLK * 16 / TPB; ++i) {  // 16 iters
        int item = tid + i * TPB;
        int tl = item >> 4, f4 = item & 15;
        int wi = idx_lds[tl];
        zq_f4[(size_t)(blockTok + tl) * 16 + f4] = emb_f4[(size_t)wi * 16 + f4];
    }
}

extern "C" void kernel_launch(void* const* d_in, const int* in_sizes, int n_in,
                              void* d_out, int out_size, void* d_ws, size_t ws_size,
                              hipStream_t stream) {
    const float* z = (const float*)d_in[0];
    const float* emb = (const float*)d_in[1];
    float* out = (float*)d_out;
    float* zq = out;                       // 131072*64 floats
    float* idx = out + (size_t)NTOK * ED;  // 131072 floats

    // ws layout: s2s (4KB) | bfH (128KB) | bfL (128KB)
    char* ws = (char*)d_ws;
    float* s2s = (float*)ws;
    unsigned short* bfH = (unsigned short*)(ws + 4096);
    unsigned short* bfL = (unsigned short*)(ws + 4096 + 131072);

    vq_prep<<<64, 128, 0, stream>>>(emb, bfH, bfL, s2s);
    vq_main<<<NTOK / MBLK, TPB, 0, stream>>>(z, emb, bfH, bfL, s2s, zq, idx);
}